// Round 1
// baseline (2489.380 us; speedup 1.0000x reference)
//
#include <hip/hip_runtime.h>

namespace {
constexpr int kB = 8;
constexpr int kC = 64;
constexpr int kN = 100000;
constexpr int kR = 32;
constexpr int kR3 = kR * kR * kR;                     // 32768
constexpr size_t kGridElems = (size_t)kB * kC * kR3;  // 16,777,216

// ws layout (bytes):
// [0, 1048576)          : unsigned counts[kB * kR3]
// [1048576, 1048576+192): double dsum[kB][3]
// [1048768, 1048768+32) : unsigned maxsq_bits[kB]
constexpr size_t kDsumOff = (size_t)kB * kR3 * sizeof(unsigned);  // 1,048,576
constexpr size_t kMaxOff = kDsumOff + (size_t)kB * 3 * sizeof(double);
constexpr size_t kWsBytes = kMaxOff + (size_t)kB * sizeof(unsigned);
}  // namespace

// ---------------- Kernel A: per-batch coordinate sums (double) ----------------
__global__ __launch_bounds__(256) void mean_kernel(const float* __restrict__ coords,
                                                   double* __restrict__ dsum) {
  const int b = blockIdx.y;
  const int tid = blockIdx.x * blockDim.x + threadIdx.x;
  const int stride = gridDim.x * blockDim.x;
  const float* cb = coords + (size_t)b * 3 * kN;
  double s0 = 0.0, s1 = 0.0, s2 = 0.0;
  for (int n = tid; n < kN; n += stride) {
    s0 += (double)cb[n];
    s1 += (double)cb[kN + n];
    s2 += (double)cb[2 * kN + n];
  }
  __shared__ double sh[3][256];
  sh[0][threadIdx.x] = s0;
  sh[1][threadIdx.x] = s1;
  sh[2][threadIdx.x] = s2;
  __syncthreads();
  for (int off = 128; off > 0; off >>= 1) {
    if (threadIdx.x < (unsigned)off) {
      sh[0][threadIdx.x] += sh[0][threadIdx.x + off];
      sh[1][threadIdx.x] += sh[1][threadIdx.x + off];
      sh[2][threadIdx.x] += sh[2][threadIdx.x + off];
    }
    __syncthreads();
  }
  if (threadIdx.x == 0) {
    atomicAdd(&dsum[b * 3 + 0], sh[0][0]);
    atomicAdd(&dsum[b * 3 + 1], sh[1][0]);
    atomicAdd(&dsum[b * 3 + 2], sh[2][0]);
  }
}

// ------------- Kernel B: per-batch max of squared norm (f32, no fma) ----------
__global__ __launch_bounds__(256) void maxnorm_kernel(const float* __restrict__ coords,
                                                      const double* __restrict__ dsum,
                                                      unsigned* __restrict__ maxbits) {
#pragma clang fp contract(off)
  const int b = blockIdx.y;
  const int tid = blockIdx.x * blockDim.x + threadIdx.x;
  const int stride = gridDim.x * blockDim.x;
  const float* cb = coords + (size_t)b * 3 * kN;
  const float m0 = (float)(dsum[b * 3 + 0] / (double)kN);
  const float m1 = (float)(dsum[b * 3 + 1] / (double)kN);
  const float m2 = (float)(dsum[b * 3 + 2] / (double)kN);
  float mx = 0.0f;
  for (int n = tid; n < kN; n += stride) {
    float x = cb[n] - m0;
    float y = cb[kN + n] - m1;
    float z = cb[2 * kN + n] - m2;
    float sx = x * x;
    float sy = y * y;
    float sz = z * z;
    float s = (sx + sy) + sz;  // match numpy's non-fused order
    mx = fmaxf(mx, s);
  }
  __shared__ float sh[256];
  sh[threadIdx.x] = mx;
  __syncthreads();
  for (int off = 128; off > 0; off >>= 1) {
    if (threadIdx.x < (unsigned)off)
      sh[threadIdx.x] = fmaxf(sh[threadIdx.x], sh[threadIdx.x + off]);
    __syncthreads();
  }
  if (threadIdx.x == 0) atomicMax(&maxbits[b], __float_as_uint(sh[0]));
}

// ------- Kernel C: norm_coords out + hash + count + 64-channel scatter --------
__global__ __launch_bounds__(256) void scatter_kernel(
    const float* __restrict__ feat, const float* __restrict__ coords,
    const double* __restrict__ dsum, const unsigned* __restrict__ maxbits,
    float* __restrict__ gridsum, float* __restrict__ out_nc,
    unsigned* __restrict__ counts) {
#pragma clang fp contract(off)
  const int b = blockIdx.y;
  const int q = blockIdx.x * blockDim.x + threadIdx.x;  // quad-of-points index
  const int n0 = q * 4;
  if (n0 >= kN) return;

  const float m0 = (float)(dsum[b * 3 + 0] / (double)kN);
  const float m1 = (float)(dsum[b * 3 + 1] / (double)kN);
  const float m2 = (float)(dsum[b * 3 + 2] / (double)kN);
  const float scale = 2.0f * sqrtf(__uint_as_float(maxbits[b]));

  const float* cb = coords + (size_t)b * 3 * kN;
  const float4 cx = *(const float4*)(cb + n0);
  const float4 cy = *(const float4*)(cb + kN + n0);
  const float4 cz = *(const float4*)(cb + 2 * kN + n0);

  float xa[4] = {cx.x, cx.y, cx.z, cx.w};
  float ya[4] = {cy.x, cy.y, cy.z, cy.w};
  float za[4] = {cz.x, cz.y, cz.z, cz.w};
  float vx[4], vy[4], vz[4];
  int h[4];
#pragma unroll
  for (int k = 0; k < 4; ++k) {
    float tx = (xa[k] - m0) / scale + 0.5f;
    float ty = (ya[k] - m1) / scale + 0.5f;
    float tz = (za[k] - m2) / scale + 0.5f;
    vx[k] = fminf(fmaxf(tx * 32.0f, 0.0f), 31.0f);
    vy[k] = fminf(fmaxf(ty * 32.0f, 0.0f), 31.0f);
    vz[k] = fminf(fmaxf(tz * 32.0f, 0.0f), 31.0f);
    int ix = (int)rintf(vx[k]);
    int iy = (int)rintf(vy[k]);
    int iz = (int)rintf(vz[k]);
    h[k] = ix * (kR * kR) + iy * kR + iz;
  }

  // norm_coords output, layout (B, 3, N)
  float* nb = out_nc + (size_t)b * 3 * kN;
  *(float4*)(nb + n0) = make_float4(vx[0], vx[1], vx[2], vx[3]);
  *(float4*)(nb + kN + n0) = make_float4(vy[0], vy[1], vy[2], vy[3]);
  *(float4*)(nb + 2 * kN + n0) = make_float4(vz[0], vz[1], vz[2], vz[3]);

  unsigned* cnt = counts + (size_t)b * kR3;
  atomicAdd(&cnt[h[0]], 1u);
  atomicAdd(&cnt[h[1]], 1u);
  atomicAdd(&cnt[h[2]], 1u);
  atomicAdd(&cnt[h[3]], 1u);

  const float* fb = feat + (size_t)b * kC * kN + n0;
  float* gb = gridsum + (size_t)b * kC * kR3;
#pragma unroll 8
  for (int c = 0; c < kC; ++c) {
    const float4 f = *(const float4*)(fb + (size_t)c * kN);
    float* g = gb + (size_t)c * kR3;
    atomicAdd(g + h[0], f.x);
    atomicAdd(g + h[1], f.y);
    atomicAdd(g + h[2], f.z);
    atomicAdd(g + h[3], f.w);
  }
}

// ---------------- Kernel D: divide by max(count, 1) in place -----------------
__global__ __launch_bounds__(256) void finalize_kernel(float* __restrict__ grid,
                                                       const unsigned* __restrict__ counts) {
  const size_t e = ((size_t)blockIdx.x * blockDim.x + threadIdx.x) * 4;
  if (e >= kGridElems) return;
  const int h = (int)(e & (size_t)(kR3 - 1));
  const int bc = (int)(e >> 15);
  const int b = bc >> 6;
  const uint4 cnt = *(const uint4*)(counts + (size_t)b * kR3 + h);
  float4 g = *(float4*)(grid + e);
  g.x = g.x / (float)(cnt.x > 1u ? cnt.x : 1u);
  g.y = g.y / (float)(cnt.y > 1u ? cnt.y : 1u);
  g.z = g.z / (float)(cnt.z > 1u ? cnt.z : 1u);
  g.w = g.w / (float)(cnt.w > 1u ? cnt.w : 1u);
  *(float4*)(grid + e) = g;
}

extern "C" void kernel_launch(void* const* d_in, const int* in_sizes, int n_in,
                              void* d_out, int out_size, void* d_ws, size_t ws_size,
                              hipStream_t stream) {
  const float* feat = (const float*)d_in[0];    // (8, 64, 100000)
  const float* coords = (const float*)d_in[1];  // (8, 3, 100000)
  float* out = (float*)d_out;
  float* gridsum = out;                  // (8, 64, 32, 32, 32)
  float* out_nc = out + kGridElems;      // (8, 3, 100000)

  unsigned* counts = (unsigned*)d_ws;
  double* dsum = (double*)((char*)d_ws + kDsumOff);
  unsigned* maxbits = (unsigned*)((char*)d_ws + kMaxOff);

  // zero the accumulators (harness poisons but never re-zeros between replays)
  hipMemsetAsync(out, 0, kGridElems * sizeof(float), stream);
  hipMemsetAsync(d_ws, 0, kWsBytes, stream);

  const dim3 blk(256);
  mean_kernel<<<dim3(32, kB), blk, 0, stream>>>(coords, dsum);
  maxnorm_kernel<<<dim3(32, kB), blk, 0, stream>>>(coords, dsum, maxbits);

  const int quads = kN / 4;  // 25000, kN % 4 == 0
  scatter_kernel<<<dim3((quads + 255) / 256, kB), blk, 0, stream>>>(
      feat, coords, dsum, maxbits, gridsum, out_nc, counts);

  const size_t vec4 = kGridElems / 4;  // 4,194,304
  finalize_kernel<<<dim3((unsigned)((vec4 + 255) / 256)), blk, 0, stream>>>(gridsum, counts);
}